// Round 10
// baseline (267.596 us; speedup 1.0000x reference)
//
#include <hip/hip_runtime.h>

#define NB 16
#define NVEC 2048
#define NDIM 32
#define NW 4
#define NHID 128
#define NCLASS 10
#define TPSZ (129 * 132)     // T slot: [129 p][132 stride] (cols 129..131 junk, never read)
#define TP4  (TPSZ / 4)      // 4257
#define USZ  (129 * 32)      // augmented U: rows 0..127 = U, row 128 = ub
#define U4   (USZ / 4)       // 1032

// tanh-approx GELU; validated absmax vs ref in prior sessions.
__device__ __forceinline__ float gelu_fast(float x) {
    float t = 1.5957691216057308f * x * (1.0f + 0.044715f * x * x);
    return x / (1.0f + __expf(-t));
}

// ---------------------------------------------------------------------------
// K1: all heavy, fully parallel work. grid 1024 x 256, LDS 68 KB -> 2/CU.
//  blocks 0..255   (type A): Û3 partial = [fw2_3; fb2_3] @ X-chunk; writes X.
//  blocks 256..1023(type B): T_j partial = [fw2_j; fb2_j] @ [h_{j+1} | 1] over
//                            a 128-m chunk (j = 2,1,0); h computed in regs.
// R9 post-mortem: 8p x 8q with per-lane 16B w-streams = 16 distinct lines/instr
// + no prefetch regs (88 VGPR) -> load-use serialization, 130us. New T-phase:
// q in lanes (acc[32p][2q]), h per-lane ds_read_b32 (conflict-free, ~1:32),
// w as wave-uniform VMEM broadcast (1 line/instr, vmcnt-pipelined).
__global__ __launch_bounds__(256) void k_big(const int* __restrict__ data,
                                             const float* __restrict__ emb,
                                             const float* __restrict__ fw1,
                                             const float* __restrict__ fb1,
                                             const float* __restrict__ fw2,
                                             const float* __restrict__ fb2,
                                             float* __restrict__ X,
                                             float* __restrict__ Tpart,
                                             float* __restrict__ U3part) {
    __shared__ float hbuf[128 * 132];    // type B: xs|w1s then ĥ; type A: xs
    __shared__ float fb2s[128];
    int tid = threadIdx.x, bx = blockIdx.x;

    if (bx < 256) {
        int b = bx >> 4, chunk = bx & 15, m0 = chunk * 128;
        const float* fw2l = fw2 + 3 * (size_t)NHID * NVEC;
        float* xs = hbuf;                // [128][36]
#pragma unroll
        for (int jj = 0; jj < 4; ++jj) {
            int i4 = tid + jj * 256;
            int r = i4 >> 3, c4 = (i4 & 7) * 4;
            int idx = data[b * NVEC + m0 + r];
            float4 v = *(const float4*)&emb[(size_t)idx * NDIM + c4];
            *(float4*)&xs[r * 36 + c4] = v;
            *(float4*)&X[((size_t)b * NVEC + m0 + r) * NDIM + c4] = v;
        }
        if (tid < 128) fb2s[tid] = fb2[3 * NVEC + m0 + tid];
        __syncthreads();
        int kg = tid & 31, d0 = (tid >> 5) * 4;
        float acc[4][4];
#pragma unroll
        for (int i = 0; i < 4; ++i)
#pragma unroll
            for (int q = 0; q < 4; ++q) acc[i][q] = 0.f;
        for (int mm = 0; mm < 128; mm += 4) {
            float4 w[4], v[4];
#pragma unroll
            for (int i = 0; i < 4; ++i)
                w[i] = *(const float4*)&fw2l[(size_t)(kg + 32 * i) * NVEC + m0 + mm];
#pragma unroll
            for (int q = 0; q < 4; ++q)
                v[q] = *(const float4*)&xs[(mm + q) * 36 + d0];   // broadcast
#pragma unroll
            for (int i = 0; i < 4; ++i) {
                const float* wf = (const float*)&w[i];
#pragma unroll
                for (int q = 0; q < 4; ++q) {
                    float wv = wf[q];
                    acc[i][0] += wv * v[q].x; acc[i][1] += wv * v[q].y;
                    acc[i][2] += wv * v[q].z; acc[i][3] += wv * v[q].w;
                }
            }
        }
        float* Up = U3part + (size_t)(b * 16 + chunk) * USZ;
#pragma unroll
        for (int i = 0; i < 4; ++i)
            *(float4*)&Up[(kg + 32 * i) * 32 + d0] =
                make_float4(acc[i][0], acc[i][1], acc[i][2], acc[i][3]);
        if (tid < 32) {
            float ca = 0.f;
#pragma unroll 8
            for (int mm = 0; mm < 128; ++mm) ca += fb2s[mm] * xs[mm * 36 + tid];
            Up[128 * 32 + tid] = ca;
        }
    } else {
        int t = bx - 256;
        int j = t >> 8, rr = t & 255;
        int b = rr >> 4, chunk = rr & 15, m0 = chunk * 128;
        const float* w1l  = fw1 + (size_t)(j + 1) * NDIM * NHID;
        const float* b1l  = fb1 + (size_t)(j + 1) * NHID;
        const float* fw2l = fw2 + (size_t)j * NHID * NVEC;
        float* xs  = hbuf;               // [128][33] scalar
        float* w1s = hbuf + 128 * 33;    // [32][132]
#pragma unroll
        for (int jj = 0; jj < 4; ++jj) {
            int i4 = tid + jj * 256;
            int r = i4 >> 3, c4 = (i4 & 7) * 4;
            int idx = data[b * NVEC + m0 + r];
            float4 v = *(const float4*)&emb[(size_t)idx * NDIM + c4];
            xs[r * 33 + c4] = v.x; xs[r * 33 + c4 + 1] = v.y;
            xs[r * 33 + c4 + 2] = v.z; xs[r * 33 + c4 + 3] = v.w;
        }
#pragma unroll
        for (int jj = 0; jj < 4; ++jj) {
            int i4 = tid + jj * 256;
            int d = i4 >> 5, c4 = (i4 & 31) * 4;
            *(float4*)&w1s[d * 132 + c4] = *(const float4*)&w1l[d * NHID + c4];
        }
        if (tid < 128) fb2s[tid] = fb2[(size_t)j * NVEC + m0 + tid];
        __syncthreads();

        // ---- h-phase (regs): thread (rg, kg): rows rg+32i x 16 k
        int rg = tid & 31, kg = tid >> 5, k0 = kg * 16;
        float hr[4][16];
        {
            float4 bq[4];
#pragma unroll
            for (int q = 0; q < 4; ++q) bq[q] = *(const float4*)&b1l[k0 + 4 * q];
#pragma unroll
            for (int i = 0; i < 4; ++i)
#pragma unroll
                for (int q = 0; q < 4; ++q) {
                    hr[i][4 * q]     = bq[q].x; hr[i][4 * q + 1] = bq[q].y;
                    hr[i][4 * q + 2] = bq[q].z; hr[i][4 * q + 3] = bq[q].w;
                }
        }
#pragma unroll 4
        for (int d = 0; d < NDIM; ++d) {
            float xv[4];
#pragma unroll
            for (int i = 0; i < 4; ++i) xv[i] = xs[(rg + 32 * i) * 33 + d];
            const float* wrow = &w1s[d * 132 + k0];          // broadcast
            float4 w0 = *(const float4*)wrow;
            float4 w1 = *(const float4*)(wrow + 4);
            float4 w2 = *(const float4*)(wrow + 8);
            float4 w3 = *(const float4*)(wrow + 12);
            float wk[16] = {w0.x, w0.y, w0.z, w0.w, w1.x, w1.y, w1.z, w1.w,
                            w2.x, w2.y, w2.z, w2.w, w3.x, w3.y, w3.z, w3.w};
#pragma unroll
            for (int i = 0; i < 4; ++i)
#pragma unroll
                for (int q = 0; q < 16; ++q) hr[i][q] += xv[i] * wk[q];
        }
        __syncthreads();                 // xs/w1s dead
        // write ĥ [m][132] + ones col 128
#pragma unroll
        for (int i = 0; i < 4; ++i) {
            int row = rg + 32 * i;
#pragma unroll
            for (int q4 = 0; q4 < 4; ++q4) {
                float4 o;
                o.x = gelu_fast(hr[i][4 * q4]);     o.y = gelu_fast(hr[i][4 * q4 + 1]);
                o.z = gelu_fast(hr[i][4 * q4 + 2]); o.w = gelu_fast(hr[i][4 * q4 + 3]);
                *(float4*)&hbuf[row * 132 + k0 + 4 * q4] = o;
            }
            if (kg == 0) hbuf[row * 132 + 128] = 1.0f;
        }
        __syncthreads();

        // ---- T-phase: wave wv owns p in [wv*32, wv*32+32); lane owns
        // q in {lane, lane+64}. w[p][m] = wave-uniform VMEM broadcast
        // (1 L1 line/instr, vmcnt-pipelined across unrolled p); h = per-lane
        // ds_read_b32, consecutive addrs (2 lanes/bank, conflict-free).
        {
            int lane = tid & 63;
            int wv = __builtin_amdgcn_readfirstlane(tid >> 6);
            int p0 = wv * 32;
            float accT[32][2];
#pragma unroll
            for (int p = 0; p < 32; ++p) { accT[p][0] = 0.f; accT[p][1] = 0.f; }
            for (int mt = 0; mt < 128; mt += 16) {
                float hreg[16][2];
#pragma unroll
                for (int mi = 0; mi < 16; ++mi) {
                    hreg[mi][0] = hbuf[(mt + mi) * 132 + lane];
                    hreg[mi][1] = hbuf[(mt + mi) * 132 + 64 + lane];
                }
#pragma unroll
                for (int p = 0; p < 32; ++p) {
                    const float4* wp =
                        (const float4*)&fw2l[(size_t)(p0 + p) * NVEC + m0 + mt];
                    float4 w0 = wp[0], w1 = wp[1], w2 = wp[2], w3 = wp[3];
                    float wk[16] = {w0.x, w0.y, w0.z, w0.w, w1.x, w1.y, w1.z, w1.w,
                                    w2.x, w2.y, w2.z, w2.w, w3.x, w3.y, w3.z, w3.w};
#pragma unroll
                    for (int mi = 0; mi < 16; ++mi) {
                        accT[p][0] += wk[mi] * hreg[mi][0];
                        accT[p][1] += wk[mi] * hreg[mi][1];
                    }
                }
            }
            float* Tp = Tpart + (size_t)t * TPSZ;
#pragma unroll
            for (int p = 0; p < 32; ++p) {
                Tp[(p0 + p) * 132 + lane]      = accT[p][0];
                Tp[(p0 + p) * 132 + 64 + lane] = accT[p][1];
            }
        }
        // tail 1: s-column (q=128) = row-sums of fw2_j chunk
        if (tid < 128) {
            float s = 0.f;
            const float* wb = &fw2l[(size_t)tid * NVEC + m0];
#pragma unroll 8
            for (int mm = 0; mm < 128; mm += 4) {
                float4 wq = *(const float4*)&wb[mm];
                s += wq.x + wq.y + wq.z + wq.w;
            }
            Tpart[(size_t)t * TPSZ + tid * 132 + 128] = s;
        }
        // tail 2: bias row (p=128) incl corner via ones col
        if (tid < 129) {
            float s = 0.f;
#pragma unroll 8
            for (int mm = 0; mm < 128; ++mm) s += fb2s[mm] * hbuf[mm * 132 + tid];
            Tpart[(size_t)t * TPSZ + 128 * 132 + tid] = s;
        }
    }
}

// ---------------------------------------------------------------------------
// K2: reduce the 16 m-chunk partials per (j,b) T and per-b Û3. grid (17,64).
__global__ __launch_bounds__(256) void k_red(const float* __restrict__ Tpart,
                                             const float* __restrict__ U3part,
                                             float* __restrict__ Tfin,
                                             float* __restrict__ U3fin) {
    int x = blockIdx.x, y = blockIdx.y, tid = threadIdx.x;
    if (y < 48) {                        // y = j*16 + b; slot = y*16 + c
        int i4 = x * 256 + tid;
        if (i4 >= TP4) return;
        float4 s = ((const float4*)Tpart)[(size_t)(y * 16) * TP4 + i4];
#pragma unroll
        for (int c = 1; c < 16; ++c) {
            float4 v = ((const float4*)Tpart)[(size_t)(y * 16 + c) * TP4 + i4];
            s.x += v.x; s.y += v.y; s.z += v.z; s.w += v.w;
        }
        ((float4*)Tfin)[(size_t)y * TP4 + i4] = s;
    } else {
        int b = y - 48;
        int i4 = x * 256 + tid;
        if (i4 >= U4) return;
        float4 s = ((const float4*)U3part)[(size_t)(b * 16) * U4 + i4];
#pragma unroll
        for (int c = 1; c < 16; ++c) {
            float4 v = ((const float4*)U3part)[(size_t)(b * 16 + c) * U4 + i4];
            s.x += v.x; s.y += v.y; s.z += v.z; s.w += v.w;
        }
        ((float4*)U3fin)[(size_t)b * U4 + i4] = s;
    }
}

// ---------------------------------------------------------------------------
// K3: the whole former serial chain. Û0 = T0 @ T1 @ T2 @ Û3, column-wise
// independent -> grid (8 dgroups, NB), each block chains its own 4 d-cols.
__global__ __launch_bounds__(256) void k_chain(const float* __restrict__ Tfin,
                                               const float* __restrict__ U3fin,
                                               const float* __restrict__ bf,
                                               float* __restrict__ U0,
                                               float* __restrict__ out) {
    __shared__ float Ul[2][129 * 4];
    int dg = blockIdx.x, b = blockIdx.y, tid = threadIdx.x;
    int d0 = dg * 4;
    if (dg == 0 && tid < NCLASS) out[b * NCLASS + tid] = bf[tid];
    if (tid < 129)
        *(float4*)&Ul[0][tid * 4] =
            *(const float4*)&U3fin[(size_t)b * USZ + tid * 32 + d0];
    int cur = 0;
    float4 acc = make_float4(0.f, 0.f, 0.f, 0.f);
    for (int j = 2; j >= 0; --j) {
        __syncthreads();
        if (tid < 129) {
            const float* rowp = Tfin + (size_t)(j * 16 + b) * TPSZ + tid * 132;
            acc = make_float4(0.f, 0.f, 0.f, 0.f);
            for (int r4 = 0; r4 < 32; ++r4) {
                float4 tv = *(const float4*)&rowp[4 * r4];
                float4 u0 = *(const float4*)&Ul[cur][(4 * r4 + 0) * 4];
                float4 u1 = *(const float4*)&Ul[cur][(4 * r4 + 1) * 4];
                float4 u2 = *(const float4*)&Ul[cur][(4 * r4 + 2) * 4];
                float4 u3 = *(const float4*)&Ul[cur][(4 * r4 + 3) * 4];
                acc.x += tv.x * u0.x + tv.y * u1.x + tv.z * u2.x + tv.w * u3.x;
                acc.y += tv.x * u0.y + tv.y * u1.y + tv.z * u2.y + tv.w * u3.y;
                acc.z += tv.x * u0.z + tv.y * u1.z + tv.z * u2.z + tv.w * u3.z;
                acc.w += tv.x * u0.w + tv.y * u1.w + tv.z * u2.w + tv.w * u3.w;
            }
            float tl = rowp[128];
            float4 ub = *(const float4*)&Ul[cur][128 * 4];
            acc.x += tl * ub.x; acc.y += tl * ub.y;
            acc.z += tl * ub.z; acc.w += tl * ub.w;
        }
        __syncthreads();
        if (tid < 129) *(float4*)&Ul[cur ^ 1][tid * 4] = acc;
        cur ^= 1;
    }
    if (tid < 129)
        *(float4*)&U0[(size_t)b * USZ + tid * 32 + d0] = acc;
}

// ---------------------------------------------------------------------------
// K4: final V = h_0 @ Û0 + classifier. grid (32, NB).
__global__ __launch_bounds__(256) void k_final(const float* __restrict__ X,
                                               const float* __restrict__ fw1,
                                               const float* __restrict__ fb1,
                                               const float* __restrict__ U0,
                                               const float* __restrict__ Wf,
                                               float* __restrict__ out) {
    __shared__ float xs[64 * 36];
    __shared__ float w1s[32 * 132];
    __shared__ float hs[64 * 132];
    __shared__ float Us[USZ];
    __shared__ float ored[4][NCLASS];
    int ng = blockIdx.x, b = blockIdx.y, tid = threadIdx.x;
    int n0 = ng * 64;
#pragma unroll
    for (int jj = 0; jj < 2; ++jj) {
        int i4 = tid + jj * 256;
        int r = i4 >> 3, c4 = (i4 & 7) * 4;
        *(float4*)&xs[r * 36 + c4] =
            *(const float4*)&X[((size_t)b * NVEC + n0 + r) * NDIM + c4];
    }
#pragma unroll
    for (int jj = 0; jj < 4; ++jj) {
        int i4 = tid + jj * 256;
        int d = i4 >> 5, c4 = (i4 & 31) * 4;
        *(float4*)&w1s[d * 132 + c4] = *(const float4*)&fw1[d * NHID + c4];
    }
    for (int i4 = tid; i4 < U4; i4 += 256)
        ((float4*)Us)[i4] = ((const float4*)(U0 + (size_t)b * USZ))[i4];
    __syncthreads();

    int rg = tid & 31;
    {   // h: rows {rg, rg+32} x 16 k
        int k0 = (tid >> 5) * 16;
        float acc[2][16];
        {
            float4 bq[4];
#pragma unroll
            for (int q = 0; q < 4; ++q) bq[q] = *(const float4*)&fb1[k0 + 4 * q];
#pragma unroll
            for (int q = 0; q < 4; ++q) {
                acc[0][4 * q] = bq[q].x; acc[0][4 * q + 1] = bq[q].y;
                acc[0][4 * q + 2] = bq[q].z; acc[0][4 * q + 3] = bq[q].w;
                acc[1][4 * q] = bq[q].x; acc[1][4 * q + 1] = bq[q].y;
                acc[1][4 * q + 2] = bq[q].z; acc[1][4 * q + 3] = bq[q].w;
            }
        }
#pragma unroll 4
        for (int d = 0; d < NDIM; ++d) {
            float x0 = xs[rg * 36 + d];
            float x1 = xs[(rg + 32) * 36 + d];
            const float* wrow = &w1s[d * 132 + k0];
            float4 w0 = *(const float4*)wrow;
            float4 w1 = *(const float4*)(wrow + 4);
            float4 w2 = *(const float4*)(wrow + 8);
            float4 w3 = *(const float4*)(wrow + 12);
            float wk[16] = {w0.x, w0.y, w0.z, w0.w, w1.x, w1.y, w1.z, w1.w,
                            w2.x, w2.y, w2.z, w2.w, w3.x, w3.y, w3.z, w3.w};
#pragma unroll
            for (int q = 0; q < 16; ++q) {
                acc[0][q] += x0 * wk[q];
                acc[1][q] += x1 * wk[q];
            }
        }
#pragma unroll
        for (int r = 0; r < 2; ++r) {
            int row = rg + 32 * r;
#pragma unroll
            for (int q4 = 0; q4 < 4; ++q4) {
                float4 o;
                o.x = gelu_fast(acc[r][4 * q4]);     o.y = gelu_fast(acc[r][4 * q4 + 1]);
                o.z = gelu_fast(acc[r][4 * q4 + 2]); o.w = gelu_fast(acc[r][4 * q4 + 3]);
                *(float4*)&hs[row * 132 + k0 + 4 * q4] = o;
            }
        }
    }
    __syncthreads();

    int dg = (tid >> 5) & 3, kh = tid >> 7;
    int d0 = dg * 8, kb = kh * 64;
    float a[2][8];
#pragma unroll
    for (int r = 0; r < 2; ++r)
#pragma unroll
        for (int q = 0; q < 8; ++q) a[r][q] = 0.f;
#pragma unroll 4
    for (int ks = 0; ks < 64; ks += 4) {
        int kk = kb + ks;
        float4 h0 = *(const float4*)&hs[rg * 132 + kk];
        float4 h1 = *(const float4*)&hs[(rg + 32) * 132 + kk];
        float4 u[4][2];
#pragma unroll
        for (int q = 0; q < 4; ++q) {
            u[q][0] = *(const float4*)&Us[(kk + q) * 32 + d0];
            u[q][1] = *(const float4*)&Us[(kk + q) * 32 + d0 + 4];
        }
        const float* hf0 = (const float*)&h0;
        const float* hf1 = (const float*)&h1;
#pragma unroll
        for (int q = 0; q < 4; ++q) {
            float v0 = hf0[q], v1 = hf1[q];
            a[0][0] += v0 * u[q][0].x; a[0][1] += v0 * u[q][0].y;
            a[0][2] += v0 * u[q][0].z; a[0][3] += v0 * u[q][0].w;
            a[0][4] += v0 * u[q][1].x; a[0][5] += v0 * u[q][1].y;
            a[0][6] += v0 * u[q][1].z; a[0][7] += v0 * u[q][1].w;
            a[1][0] += v1 * u[q][0].x; a[1][1] += v1 * u[q][0].y;
            a[1][2] += v1 * u[q][0].z; a[1][3] += v1 * u[q][0].w;
            a[1][4] += v1 * u[q][1].x; a[1][5] += v1 * u[q][1].y;
            a[1][6] += v1 * u[q][1].z; a[1][7] += v1 * u[q][1].w;
        }
    }
    if (kh == 1) {
#pragma unroll
        for (int r = 0; r < 2; ++r) {
            float* p = &xs[(rg + 32 * r) * 36 + d0];
            *(float4*)p       = make_float4(a[r][0], a[r][1], a[r][2], a[r][3]);
            *(float4*)(p + 4) = make_float4(a[r][4], a[r][5], a[r][6], a[r][7]);
        }
    }
    __syncthreads();
    float accC[NCLASS];
#pragma unroll
    for (int c = 0; c < NCLASS; ++c) accC[c] = 0.f;
    if (kh == 0) {
        float4 ub0 = *(const float4*)&Us[128 * 32 + d0];
        float4 ub1 = *(const float4*)&Us[128 * 32 + d0 + 4];
#pragma unroll
        for (int r = 0; r < 2; ++r) {
            const float* p = &xs[(rg + 32 * r) * 36 + d0];
            float4 p0 = *(const float4*)p;
            float4 p1 = *(const float4*)(p + 4);
            a[r][0] += p0.x + ub0.x; a[r][1] += p0.y + ub0.y;
            a[r][2] += p0.z + ub0.z; a[r][3] += p0.w + ub0.w;
            a[r][4] += p1.x + ub1.x; a[r][5] += p1.y + ub1.y;
            a[r][6] += p1.z + ub1.z; a[r][7] += p1.w + ub1.w;
            int nrow = n0 + rg + 32 * r;
#pragma unroll
            for (int dd = 0; dd < 8; ++dd) {
                float v = a[r][dd];
                const float2* wr =
                    (const float2*)(Wf + ((size_t)nrow * 32 + d0 + dd) * NCLASS);
#pragma unroll
                for (int p5 = 0; p5 < 5; ++p5) {
                    float2 w = wr[p5];
                    accC[2 * p5]     += v * w.x;
                    accC[2 * p5 + 1] += v * w.y;
                }
            }
        }
    }
#pragma unroll
    for (int c = 0; c < NCLASS; ++c)
#pragma unroll
        for (int off = 32; off >= 1; off >>= 1)
            accC[c] += __shfl_down(accC[c], off, 64);
    int w = tid >> 6;
    if ((tid & 63) == 0) {
#pragma unroll
        for (int c = 0; c < NCLASS; ++c) ored[w][c] = accC[c];
    }
    __syncthreads();
    if (tid < NCLASS)
        atomicAdd(&out[b * NCLASS + tid],
                  ored[0][tid] + ored[1][tid] + ored[2][tid] + ored[3][tid]);
}

// ---------------------------------------------------------------------------
extern "C" void kernel_launch(void* const* d_in, const int* in_sizes, int n_in,
                              void* d_out, int out_size, void* d_ws, size_t ws_size,
                              hipStream_t stream) {
    const int*   data = (const int*)d_in[0];
    const float* emb  = (const float*)d_in[1];
    const float* fw1  = (const float*)d_in[2];
    const float* fb1  = (const float*)d_in[3];
    const float* fw2  = (const float*)d_in[4];
    const float* fb2  = (const float*)d_in[5];
    const float* Wf   = (const float*)d_in[6];
    const float* bf   = (const float*)d_in[7];
    float* out = (float*)d_out;

    float* X      = (float*)d_ws;                       // 1,048,576 floats
    float* Tpart  = X + (size_t)NB * NVEC * NDIM;       // 768*17028 = 13,077,504
    float* U3part = Tpart + (size_t)768 * TPSZ;         // 256*4128  =  1,056,768
    float* Tfin   = U3part + (size_t)256 * USZ;         // 48*17028  =    817,344
    float* U3fin  = Tfin + (size_t)48 * TPSZ;           // 16*4128
    float* U0     = U3fin + (size_t)NB * USZ;           // 16*4128

    k_big<<<1024, 256, 0, stream>>>(data, emb, fw1, fb1, fw2, fb2, X, Tpart, U3part);
    k_red<<<dim3(17, 64), 256, 0, stream>>>(Tpart, U3part, Tfin, U3fin);
    k_chain<<<dim3(8, NB), 256, 0, stream>>>(Tfin, U3fin, bf, U0, out);
    k_final<<<dim3(32, NB), 256, 0, stream>>>(X, fw1, fb1, U0, Wf, out);
}

// Round 11
// 202.627 us; speedup vs baseline: 1.3206x; 1.3206x over previous
//
#include <hip/hip_runtime.h>

#define NB 16
#define NVEC 2048
#define NDIM 32
#define NW 4
#define NHID 128
#define NCLASS 10
#define TPSZ (129 * 132)     // T slot: [129 p][132 stride] (cols 129..131 junk, never read)
#define TP4  (TPSZ / 4)      // 4257
#define USZ  (129 * 32)      // augmented U: rows 0..127 = U, row 128 = ub
#define U4   (USZ / 4)       // 1032

// tanh-approx GELU; validated absmax vs ref in prior sessions.
__device__ __forceinline__ float gelu_fast(float x) {
    float t = 1.5957691216057308f * x * (1.0f + 0.044715f * x * x);
    return x / (1.0f + __expf(-t));
}

// ---------------------------------------------------------------------------
// K1: all heavy, fully parallel work. grid 1024 x 256, LDS 132.5 KB -> 1/CU,
// launch_bounds(256,1): 1 wave/SIMD -> up to 512 VGPR, no allocator squeeze
// (R9/R10 post-mortem: 88-reg cap caused spills/serialization).
//  blocks 0..255   (type A): Û3 partial = [fw2_3; fb2_3] @ X-chunk; writes X.
//  blocks 256..1023(type B): T_j partial = [fw2_j; fb2_j] @ [ĥ_{j+1} | 1] over
//    a 128-m chunk. T-phase: BOTH operands in LDS (R10 lesson: broadcast from
//    LDS, never global); thread tile 8p x 8q; per 4-m: 8 w-b128 (p interleaved
//    +16 -> 2-way=free) + 8 h-b128 (4 q-tiles/wave at bank slots {0,8,16,24}
//    -> clean) per 256 FMA-instr.
__global__ __launch_bounds__(256, 1) void k_big(const int* __restrict__ data,
                                                const float* __restrict__ emb,
                                                const float* __restrict__ fw1,
                                                const float* __restrict__ fb1,
                                                const float* __restrict__ fw2,
                                                const float* __restrict__ fb2,
                                                float* __restrict__ X,
                                                float* __restrict__ Tpart,
                                                float* __restrict__ U3part) {
    __shared__ float hbuf[128 * 132];    // type B: xs|w1s then ĥ; type A: xs
    __shared__ float ws[128 * 132];      // type B: w[p][m] chunk (staged once)
    __shared__ float fb2s[128];
    int tid = threadIdx.x, bx = blockIdx.x;

    if (bx < 256) {
        int b = bx >> 4, chunk = bx & 15, m0 = chunk * 128;
        const float* fw2l = fw2 + 3 * (size_t)NHID * NVEC;
        float* xs = hbuf;                // [128][36]
#pragma unroll
        for (int jj = 0; jj < 4; ++jj) {
            int i4 = tid + jj * 256;
            int r = i4 >> 3, c4 = (i4 & 7) * 4;
            int idx = data[b * NVEC + m0 + r];
            float4 v = *(const float4*)&emb[(size_t)idx * NDIM + c4];
            *(float4*)&xs[r * 36 + c4] = v;
            *(float4*)&X[((size_t)b * NVEC + m0 + r) * NDIM + c4] = v;
        }
        if (tid < 128) fb2s[tid] = fb2[3 * NVEC + m0 + tid];
        __syncthreads();
        int kg = tid & 31, d0 = (tid >> 5) * 4;
        float acc[4][4];
#pragma unroll
        for (int i = 0; i < 4; ++i)
#pragma unroll
            for (int q = 0; q < 4; ++q) acc[i][q] = 0.f;
        for (int mm = 0; mm < 128; mm += 4) {
            float4 w[4], v[4];
#pragma unroll
            for (int i = 0; i < 4; ++i)
                w[i] = *(const float4*)&fw2l[(size_t)(kg + 32 * i) * NVEC + m0 + mm];
#pragma unroll
            for (int q = 0; q < 4; ++q)
                v[q] = *(const float4*)&xs[(mm + q) * 36 + d0];   // broadcast
#pragma unroll
            for (int i = 0; i < 4; ++i) {
                const float* wf = (const float*)&w[i];
#pragma unroll
                for (int q = 0; q < 4; ++q) {
                    float wv = wf[q];
                    acc[i][0] += wv * v[q].x; acc[i][1] += wv * v[q].y;
                    acc[i][2] += wv * v[q].z; acc[i][3] += wv * v[q].w;
                }
            }
        }
        float* Up = U3part + (size_t)(b * 16 + chunk) * USZ;
#pragma unroll
        for (int i = 0; i < 4; ++i)
            *(float4*)&Up[(kg + 32 * i) * 32 + d0] =
                make_float4(acc[i][0], acc[i][1], acc[i][2], acc[i][3]);
        if (tid < 32) {
            float ca = 0.f;
#pragma unroll 8
            for (int mm = 0; mm < 128; ++mm) ca += fb2s[mm] * xs[mm * 36 + tid];
            Up[128 * 32 + tid] = ca;
        }
    } else {
        int t = bx - 256;
        int j = t >> 8, rr = t & 255;
        int b = rr >> 4, chunk = rr & 15, m0 = chunk * 128;
        const float* w1l  = fw1 + (size_t)(j + 1) * NDIM * NHID;
        const float* b1l  = fb1 + (size_t)(j + 1) * NHID;
        const float* fw2l = fw2 + (size_t)j * NHID * NVEC;
        float* xs  = hbuf;               // [128][33] scalar
        float* w1s = hbuf + 128 * 33;    // [32][132]
#pragma unroll
        for (int jj = 0; jj < 4; ++jj) {
            int i4 = tid + jj * 256;
            int r = i4 >> 3, c4 = (i4 & 7) * 4;
            int idx = data[b * NVEC + m0 + r];
            float4 v = *(const float4*)&emb[(size_t)idx * NDIM + c4];
            xs[r * 33 + c4] = v.x; xs[r * 33 + c4 + 1] = v.y;
            xs[r * 33 + c4 + 2] = v.z; xs[r * 33 + c4 + 3] = v.w;
        }
#pragma unroll
        for (int jj = 0; jj < 4; ++jj) {
            int i4 = tid + jj * 256;
            int d = i4 >> 5, c4 = (i4 & 31) * 4;
            *(float4*)&w1s[d * 132 + c4] = *(const float4*)&w1l[d * NHID + c4];
        }
        // stage the full fw2 chunk: ws[p][m], coalesced global f4 reads
#pragma unroll
        for (int jj = 0; jj < 16; ++jj) {
            int i4 = tid + jj * 256;             // 4096 f4 = 128 p x 32 f4
            int p = i4 >> 5, c4 = (i4 & 31) * 4;
            *(float4*)&ws[p * 132 + c4] =
                *(const float4*)&fw2l[(size_t)p * NVEC + m0 + c4];
        }
        if (tid < 128) fb2s[tid] = fb2[(size_t)j * NVEC + m0 + tid];
        __syncthreads();

        // ---- h-phase (regs): thread (rg, kg): rows rg+32i x 16 k
        int rg = tid & 31, kg = tid >> 5, k0 = kg * 16;
        float hr[4][16];
        {
            float4 bq[4];
#pragma unroll
            for (int q = 0; q < 4; ++q) bq[q] = *(const float4*)&b1l[k0 + 4 * q];
#pragma unroll
            for (int i = 0; i < 4; ++i)
#pragma unroll
                for (int q = 0; q < 4; ++q) {
                    hr[i][4 * q]     = bq[q].x; hr[i][4 * q + 1] = bq[q].y;
                    hr[i][4 * q + 2] = bq[q].z; hr[i][4 * q + 3] = bq[q].w;
                }
        }
#pragma unroll 4
        for (int d = 0; d < NDIM; ++d) {
            float xv[4];
#pragma unroll
            for (int i = 0; i < 4; ++i) xv[i] = xs[(rg + 32 * i) * 33 + d];
            const float* wrow = &w1s[d * 132 + k0];          // broadcast
            float4 w0 = *(const float4*)wrow;
            float4 w1 = *(const float4*)(wrow + 4);
            float4 w2 = *(const float4*)(wrow + 8);
            float4 w3 = *(const float4*)(wrow + 12);
            float wk[16] = {w0.x, w0.y, w0.z, w0.w, w1.x, w1.y, w1.z, w1.w,
                            w2.x, w2.y, w2.z, w2.w, w3.x, w3.y, w3.z, w3.w};
#pragma unroll
            for (int i = 0; i < 4; ++i)
#pragma unroll
                for (int q = 0; q < 16; ++q) hr[i][q] += xv[i] * wk[q];
        }
        __syncthreads();                 // xs/w1s dead
        // write ĥ [m][132] + ones col 128
#pragma unroll
        for (int i = 0; i < 4; ++i) {
            int row = rg + 32 * i;
#pragma unroll
            for (int q4 = 0; q4 < 4; ++q4) {
                float4 o;
                o.x = gelu_fast(hr[i][4 * q4]);     o.y = gelu_fast(hr[i][4 * q4 + 1]);
                o.z = gelu_fast(hr[i][4 * q4 + 2]); o.w = gelu_fast(hr[i][4 * q4 + 3]);
                *(float4*)&hbuf[row * 132 + k0 + 4 * q4] = o;
            }
            if (kg == 0) hbuf[row * 132 + 128] = 1.0f;
        }
        __syncthreads();

        // ---- T-phase: thread (pg, qg) = (tid&15, tid>>4): 8p x 8q, both
        // operands from LDS. m ascending (same accumulation order as R7).
        {
            int pg = tid & 15, q0 = (tid >> 4) * 8;
            float acc[8][8];
#pragma unroll
            for (int i = 0; i < 8; ++i)
#pragma unroll
                for (int q = 0; q < 8; ++q) acc[i][q] = 0.f;
            for (int mt = 0; mt < 128; mt += 4) {
                float4 wv4[8];
#pragma unroll
                for (int i = 0; i < 8; ++i)
                    wv4[i] = *(const float4*)&ws[(pg + 16 * i) * 132 + mt];
                float4 ha[4], hb[4];
#pragma unroll
                for (int mm = 0; mm < 4; ++mm) {
                    ha[mm] = *(const float4*)&hbuf[(mt + mm) * 132 + q0];
                    hb[mm] = *(const float4*)&hbuf[(mt + mm) * 132 + q0 + 4];
                }
#pragma unroll
                for (int i = 0; i < 8; ++i) {
                    const float* wf = (const float*)&wv4[i];
#pragma unroll
                    for (int mm = 0; mm < 4; ++mm) {
                        float w = wf[mm];
                        acc[i][0] += w * ha[mm].x; acc[i][1] += w * ha[mm].y;
                        acc[i][2] += w * ha[mm].z; acc[i][3] += w * ha[mm].w;
                        acc[i][4] += w * hb[mm].x; acc[i][5] += w * hb[mm].y;
                        acc[i][6] += w * hb[mm].z; acc[i][7] += w * hb[mm].w;
                    }
                }
            }
            float* Tp = Tpart + (size_t)t * TPSZ;
#pragma unroll
            for (int i = 0; i < 8; ++i) {
                *(float4*)&Tp[(pg + 16 * i) * 132 + q0] =
                    make_float4(acc[i][0], acc[i][1], acc[i][2], acc[i][3]);
                *(float4*)&Tp[(pg + 16 * i) * 132 + q0 + 4] =
                    make_float4(acc[i][4], acc[i][5], acc[i][6], acc[i][7]);
            }
        }
        // tail 1: s-column (q=128) = row-sums of fw2_j chunk
        if (tid < 128) {
            float s = 0.f;
            const float* wb = &fw2l[(size_t)tid * NVEC + m0];
#pragma unroll 8
            for (int mm = 0; mm < 128; mm += 4) {
                float4 wq = *(const float4*)&wb[mm];
                s += wq.x + wq.y + wq.z + wq.w;
            }
            Tpart[(size_t)t * TPSZ + tid * 132 + 128] = s;
        }
        // tail 2: bias row (p=128) incl corner via ones col
        if (tid < 129) {
            float s = 0.f;
#pragma unroll 8
            for (int mm = 0; mm < 128; ++mm) s += fb2s[mm] * hbuf[mm * 132 + tid];
            Tpart[(size_t)t * TPSZ + 128 * 132 + tid] = s;
        }
    }
}

// ---------------------------------------------------------------------------
// K2: reduce the 16 m-chunk partials per (j,b) T and per-b Û3. grid (17,64).
__global__ __launch_bounds__(256) void k_red(const float* __restrict__ Tpart,
                                             const float* __restrict__ U3part,
                                             float* __restrict__ Tfin,
                                             float* __restrict__ U3fin) {
    int x = blockIdx.x, y = blockIdx.y, tid = threadIdx.x;
    if (y < 48) {                        // y = j*16 + b; slot = y*16 + c
        int i4 = x * 256 + tid;
        if (i4 >= TP4) return;
        float4 s = ((const float4*)Tpart)[(size_t)(y * 16) * TP4 + i4];
#pragma unroll
        for (int c = 1; c < 16; ++c) {
            float4 v = ((const float4*)Tpart)[(size_t)(y * 16 + c) * TP4 + i4];
            s.x += v.x; s.y += v.y; s.z += v.z; s.w += v.w;
        }
        ((float4*)Tfin)[(size_t)y * TP4 + i4] = s;
    } else {
        int b = y - 48;
        int i4 = x * 256 + tid;
        if (i4 >= U4) return;
        float4 s = ((const float4*)U3part)[(size_t)(b * 16) * U4 + i4];
#pragma unroll
        for (int c = 1; c < 16; ++c) {
            float4 v = ((const float4*)U3part)[(size_t)(b * 16 + c) * U4 + i4];
            s.x += v.x; s.y += v.y; s.z += v.z; s.w += v.w;
        }
        ((float4*)U3fin)[(size_t)b * U4 + i4] = s;
    }
}

// ---------------------------------------------------------------------------
// K3: the whole former serial chain. Û0 = T0 @ T1 @ T2 @ Û3, column-wise
// independent -> grid (8 dgroups, NB), each block chains its own 4 d-cols.
__global__ __launch_bounds__(256) void k_chain(const float* __restrict__ Tfin,
                                               const float* __restrict__ U3fin,
                                               const float* __restrict__ bf,
                                               float* __restrict__ U0,
                                               float* __restrict__ out) {
    __shared__ float Ul[2][129 * 4];
    int dg = blockIdx.x, b = blockIdx.y, tid = threadIdx.x;
    int d0 = dg * 4;
    if (dg == 0 && tid < NCLASS) out[b * NCLASS + tid] = bf[tid];
    if (tid < 129)
        *(float4*)&Ul[0][tid * 4] =
            *(const float4*)&U3fin[(size_t)b * USZ + tid * 32 + d0];
    int cur = 0;
    float4 acc = make_float4(0.f, 0.f, 0.f, 0.f);
    for (int j = 2; j >= 0; --j) {
        __syncthreads();
        if (tid < 129) {
            const float* rowp = Tfin + (size_t)(j * 16 + b) * TPSZ + tid * 132;
            acc = make_float4(0.f, 0.f, 0.f, 0.f);
            for (int r4 = 0; r4 < 32; ++r4) {
                float4 tv = *(const float4*)&rowp[4 * r4];
                float4 u0 = *(const float4*)&Ul[cur][(4 * r4 + 0) * 4];
                float4 u1 = *(const float4*)&Ul[cur][(4 * r4 + 1) * 4];
                float4 u2 = *(const float4*)&Ul[cur][(4 * r4 + 2) * 4];
                float4 u3 = *(const float4*)&Ul[cur][(4 * r4 + 3) * 4];
                acc.x += tv.x * u0.x + tv.y * u1.x + tv.z * u2.x + tv.w * u3.x;
                acc.y += tv.x * u0.y + tv.y * u1.y + tv.z * u2.y + tv.w * u3.y;
                acc.z += tv.x * u0.z + tv.y * u1.z + tv.z * u2.z + tv.w * u3.z;
                acc.w += tv.x * u0.w + tv.y * u1.w + tv.z * u2.w + tv.w * u3.w;
            }
            float tl = rowp[128];
            float4 ub = *(const float4*)&Ul[cur][128 * 4];
            acc.x += tl * ub.x; acc.y += tl * ub.y;
            acc.z += tl * ub.z; acc.w += tl * ub.w;
        }
        __syncthreads();
        if (tid < 129) *(float4*)&Ul[cur ^ 1][tid * 4] = acc;
        cur ^= 1;
    }
    if (tid < 129)
        *(float4*)&U0[(size_t)b * USZ + tid * 32 + d0] = acc;
}

// ---------------------------------------------------------------------------
// K4: final V = h_0 @ Û0 + classifier. grid (32, NB).
__global__ __launch_bounds__(256) void k_final(const float* __restrict__ X,
                                               const float* __restrict__ fw1,
                                               const float* __restrict__ fb1,
                                               const float* __restrict__ U0,
                                               const float* __restrict__ Wf,
                                               float* __restrict__ out) {
    __shared__ float xs[64 * 36];
    __shared__ float w1s[32 * 132];
    __shared__ float hs[64 * 132];
    __shared__ float Us[USZ];
    __shared__ float ored[4][NCLASS];
    int ng = blockIdx.x, b = blockIdx.y, tid = threadIdx.x;
    int n0 = ng * 64;
#pragma unroll
    for (int jj = 0; jj < 2; ++jj) {
        int i4 = tid + jj * 256;
        int r = i4 >> 3, c4 = (i4 & 7) * 4;
        *(float4*)&xs[r * 36 + c4] =
            *(const float4*)&X[((size_t)b * NVEC + n0 + r) * NDIM + c4];
    }
#pragma unroll
    for (int jj = 0; jj < 4; ++jj) {
        int i4 = tid + jj * 256;
        int d = i4 >> 5, c4 = (i4 & 31) * 4;
        *(float4*)&w1s[d * 132 + c4] = *(const float4*)&fw1[d * NHID + c4];
    }
    for (int i4 = tid; i4 < U4; i4 += 256)
        ((float4*)Us)[i4] = ((const float4*)(U0 + (size_t)b * USZ))[i4];
    __syncthreads();

    int rg = tid & 31;
    {   // h: rows {rg, rg+32} x 16 k
        int k0 = (tid >> 5) * 16;
        float acc[2][16];
        {
            float4 bq[4];
#pragma unroll
            for (int q = 0; q < 4; ++q) bq[q] = *(const float4*)&fb1[k0 + 4 * q];
#pragma unroll
            for (int q = 0; q < 4; ++q) {
                acc[0][4 * q] = bq[q].x; acc[0][4 * q + 1] = bq[q].y;
                acc[0][4 * q + 2] = bq[q].z; acc[0][4 * q + 3] = bq[q].w;
                acc[1][4 * q] = bq[q].x; acc[1][4 * q + 1] = bq[q].y;
                acc[1][4 * q + 2] = bq[q].z; acc[1][4 * q + 3] = bq[q].w;
            }
        }
#pragma unroll 4
        for (int d = 0; d < NDIM; ++d) {
            float x0 = xs[rg * 36 + d];
            float x1 = xs[(rg + 32) * 36 + d];
            const float* wrow = &w1s[d * 132 + k0];
            float4 w0 = *(const float4*)wrow;
            float4 w1 = *(const float4*)(wrow + 4);
            float4 w2 = *(const float4*)(wrow + 8);
            float4 w3 = *(const float4*)(wrow + 12);
            float wk[16] = {w0.x, w0.y, w0.z, w0.w, w1.x, w1.y, w1.z, w1.w,
                            w2.x, w2.y, w2.z, w2.w, w3.x, w3.y, w3.z, w3.w};
#pragma unroll
            for (int q = 0; q < 16; ++q) {
                acc[0][q] += x0 * wk[q];
                acc[1][q] += x1 * wk[q];
            }
        }
#pragma unroll
        for (int r = 0; r < 2; ++r) {
            int row = rg + 32 * r;
#pragma unroll
            for (int q4 = 0; q4 < 4; ++q4) {
                float4 o;
                o.x = gelu_fast(acc[r][4 * q4]);     o.y = gelu_fast(acc[r][4 * q4 + 1]);
                o.z = gelu_fast(acc[r][4 * q4 + 2]); o.w = gelu_fast(acc[r][4 * q4 + 3]);
                *(float4*)&hs[row * 132 + k0 + 4 * q4] = o;
            }
        }
    }
    __syncthreads();

    int dg = (tid >> 5) & 3, kh = tid >> 7;
    int d0 = dg * 8, kb = kh * 64;
    float a[2][8];
#pragma unroll
    for (int r = 0; r < 2; ++r)
#pragma unroll
        for (int q = 0; q < 8; ++q) a[r][q] = 0.f;
#pragma unroll 4
    for (int ks = 0; ks < 64; ks += 4) {
        int kk = kb + ks;
        float4 h0 = *(const float4*)&hs[rg * 132 + kk];
        float4 h1 = *(const float4*)&hs[(rg + 32) * 132 + kk];
        float4 u[4][2];
#pragma unroll
        for (int q = 0; q < 4; ++q) {
            u[q][0] = *(const float4*)&Us[(kk + q) * 32 + d0];
            u[q][1] = *(const float4*)&Us[(kk + q) * 32 + d0 + 4];
        }
        const float* hf0 = (const float*)&h0;
        const float* hf1 = (const float*)&h1;
#pragma unroll
        for (int q = 0; q < 4; ++q) {
            float v0 = hf0[q], v1 = hf1[q];
            a[0][0] += v0 * u[q][0].x; a[0][1] += v0 * u[q][0].y;
            a[0][2] += v0 * u[q][0].z; a[0][3] += v0 * u[q][0].w;
            a[0][4] += v0 * u[q][1].x; a[0][5] += v0 * u[q][1].y;
            a[0][6] += v0 * u[q][1].z; a[0][7] += v0 * u[q][1].w;
            a[1][0] += v1 * u[q][0].x; a[1][1] += v1 * u[q][0].y;
            a[1][2] += v1 * u[q][0].z; a[1][3] += v1 * u[q][0].w;
            a[1][4] += v1 * u[q][1].x; a[1][5] += v1 * u[q][1].y;
            a[1][6] += v1 * u[q][1].z; a[1][7] += v1 * u[q][1].w;
        }
    }
    if (kh == 1) {
#pragma unroll
        for (int r = 0; r < 2; ++r) {
            float* p = &xs[(rg + 32 * r) * 36 + d0];
            *(float4*)p       = make_float4(a[r][0], a[r][1], a[r][2], a[r][3]);
            *(float4*)(p + 4) = make_float4(a[r][4], a[r][5], a[r][6], a[r][7]);
        }
    }
    __syncthreads();
    float accC[NCLASS];
#pragma unroll
    for (int c = 0; c < NCLASS; ++c) accC[c] = 0.f;
    if (kh == 0) {
        float4 ub0 = *(const float4*)&Us[128 * 32 + d0];
        float4 ub1 = *(const float4*)&Us[128 * 32 + d0 + 4];
#pragma unroll
        for (int r = 0; r < 2; ++r) {
            const float* p = &xs[(rg + 32 * r) * 36 + d0];
            float4 p0 = *(const float4*)p;
            float4 p1 = *(const float4*)(p + 4);
            a[r][0] += p0.x + ub0.x; a[r][1] += p0.y + ub0.y;
            a[r][2] += p0.z + ub0.z; a[r][3] += p0.w + ub0.w;
            a[r][4] += p1.x + ub1.x; a[r][5] += p1.y + ub1.y;
            a[r][6] += p1.z + ub1.z; a[r][7] += p1.w + ub1.w;
            int nrow = n0 + rg + 32 * r;
#pragma unroll
            for (int dd = 0; dd < 8; ++dd) {
                float v = a[r][dd];
                const float2* wr =
                    (const float2*)(Wf + ((size_t)nrow * 32 + d0 + dd) * NCLASS);
#pragma unroll
                for (int p5 = 0; p5 < 5; ++p5) {
                    float2 w = wr[p5];
                    accC[2 * p5]     += v * w.x;
                    accC[2 * p5 + 1] += v * w.y;
                }
            }
        }
    }
#pragma unroll
    for (int c = 0; c < NCLASS; ++c)
#pragma unroll
        for (int off = 32; off >= 1; off >>= 1)
            accC[c] += __shfl_down(accC[c], off, 64);
    int w = tid >> 6;
    if ((tid & 63) == 0) {
#pragma unroll
        for (int c = 0; c < NCLASS; ++c) ored[w][c] = accC[c];
    }
    __syncthreads();
    if (tid < NCLASS)
        atomicAdd(&out[b * NCLASS + tid],
                  ored[0][tid] + ored[1][tid] + ored[2][tid] + ored[3][tid]);
}

// ---------------------------------------------------------------------------
extern "C" void kernel_launch(void* const* d_in, const int* in_sizes, int n_in,
                              void* d_out, int out_size, void* d_ws, size_t ws_size,
                              hipStream_t stream) {
    const int*   data = (const int*)d_in[0];
    const float* emb  = (const float*)d_in[1];
    const float* fw1  = (const float*)d_in[2];
    const float* fb1  = (const float*)d_in[3];
    const float* fw2  = (const float*)d_in[4];
    const float* fb2  = (const float*)d_in[5];
    const float* Wf   = (const float*)d_in[6];
    const float* bf   = (const float*)d_in[7];
    float* out = (float*)d_out;

    float* X      = (float*)d_ws;                       // 1,048,576 floats
    float* Tpart  = X + (size_t)NB * NVEC * NDIM;       // 768*17028 = 13,077,504
    float* U3part = Tpart + (size_t)768 * TPSZ;         // 256*4128  =  1,056,768
    float* Tfin   = U3part + (size_t)256 * USZ;         // 48*17028  =    817,344
    float* U3fin  = Tfin + (size_t)48 * TPSZ;           // 16*4128
    float* U0     = U3fin + (size_t)NB * USZ;           // 16*4128

    k_big<<<1024, 256, 0, stream>>>(data, emb, fw1, fb1, fw2, fb2, X, Tpart, U3part);
    k_red<<<dim3(17, 64), 256, 0, stream>>>(Tpart, U3part, Tfin, U3fin);
    k_chain<<<dim3(8, NB), 256, 0, stream>>>(Tfin, U3fin, bf, U0, out);
    k_final<<<dim3(32, NB), 256, 0, stream>>>(X, fw1, fb1, U0, Wf, out);
}

// Round 12
// 196.247 us; speedup vs baseline: 1.3636x; 1.0325x over previous
//
#include <hip/hip_runtime.h>

#define NB 16
#define NVEC 2048
#define NDIM 32
#define NW 4
#define NHID 128
#define NCLASS 10
#define TPSZ (129 * 132)     // T slot: [129 p][132 stride] (cols 129..131 junk, never read)
#define TP4  (TPSZ / 4)      // 4257
#define USZ  (129 * 32)      // augmented U: rows 0..127 = U, row 128 = ub
#define U4   (USZ / 4)       // 1032

// tanh-approx GELU; validated absmax vs ref in prior sessions.
__device__ __forceinline__ float gelu_fast(float x) {
    float t = 1.5957691216057308f * x * (1.0f + 0.044715f * x * x);
    return x / (1.0f + __expf(-t));
}

// ---------------------------------------------------------------------------
// K1: grid 1024 x 512, LDS 135.7 KB -> 1 block/CU but 8 waves (2/SIMD).
// R11 post-mortem: all-LDS operands were right, but 256 thr = 1 wave/SIMD
// exposed every ds_read->FMA dep (VALUBusy 38%). 512 thr + m-split (mh) gives
// 2 waves/SIMD so LDS pipe (~24.6K cyc/blk) and FMA (~16.4K cyc/SIMD) overlap.
//  blocks 0..255   (type A): U3 partial = [fw2_3; fb2_3] @ X-chunk; writes X.
//  blocks 256..1023(type B): T_j partial over a 128-m chunk; h in regs -> LDS;
//    T-phase 8p x 8q x 64m per thread, both operands LDS, merge via ws.
__global__ __launch_bounds__(512, 2) void k_big(const int* __restrict__ data,
                                                const float* __restrict__ emb,
                                                const float* __restrict__ fw1,
                                                const float* __restrict__ fb1,
                                                const float* __restrict__ fw2,
                                                const float* __restrict__ fb2,
                                                float* __restrict__ X,
                                                float* __restrict__ Tpart,
                                                float* __restrict__ U3part) {
    __shared__ float hbuf[128 * 132];    // type B: xs|w1s then h-hat; type A: xs
    __shared__ float ws[128 * 132];      // type B: w[p][m] chunk; then merge buf
    __shared__ float fb2s[128];
    int tid = threadIdx.x, bx = blockIdx.x;

    if (bx < 256) {
        int b = bx >> 4, chunk = bx & 15, m0 = chunk * 128;
        const float* fw2l = fw2 + 3 * (size_t)NHID * NVEC;
        float* xs = hbuf;                // [128][36]
#pragma unroll
        for (int jj = 0; jj < 2; ++jj) {
            int i4 = tid + jj * 512;     // 1024 f4 = 128 rows x 8 f4
            int r = i4 >> 3, c4 = (i4 & 7) * 4;
            int idx = data[b * NVEC + m0 + r];
            float4 v = *(const float4*)&emb[(size_t)idx * NDIM + c4];
            *(float4*)&xs[r * 36 + c4] = v;
            *(float4*)&X[((size_t)b * NVEC + m0 + r) * NDIM + c4] = v;
        }
        if (tid < 128) fb2s[tid] = fb2[3 * NVEC + m0 + tid];
        __syncthreads();
        int kg = tid & 63, d0 = (tid >> 6) * 4;   // 2k x 4d per thread
        float acc[2][4];
#pragma unroll
        for (int i = 0; i < 2; ++i)
#pragma unroll
            for (int q = 0; q < 4; ++q) acc[i][q] = 0.f;
        for (int mm = 0; mm < 128; mm += 4) {
            float4 w[2], v[4];
#pragma unroll
            for (int i = 0; i < 2; ++i)
                w[i] = *(const float4*)&fw2l[(size_t)(kg + 64 * i) * NVEC + m0 + mm];
#pragma unroll
            for (int q = 0; q < 4; ++q)
                v[q] = *(const float4*)&xs[(mm + q) * 36 + d0];   // broadcast
#pragma unroll
            for (int i = 0; i < 2; ++i) {
                const float* wf = (const float*)&w[i];
#pragma unroll
                for (int q = 0; q < 4; ++q) {
                    float wv = wf[q];
                    acc[i][0] += wv * v[q].x; acc[i][1] += wv * v[q].y;
                    acc[i][2] += wv * v[q].z; acc[i][3] += wv * v[q].w;
                }
            }
        }
        float* Up = U3part + (size_t)(b * 16 + chunk) * USZ;
#pragma unroll
        for (int i = 0; i < 2; ++i)
            *(float4*)&Up[(kg + 64 * i) * 32 + d0] =
                make_float4(acc[i][0], acc[i][1], acc[i][2], acc[i][3]);
        if (tid < 32) {
            float ca = 0.f;
#pragma unroll 8
            for (int mm = 0; mm < 128; ++mm) ca += fb2s[mm] * xs[mm * 36 + tid];
            Up[128 * 32 + tid] = ca;
        }
    } else {
        int t = bx - 256;
        int j = t >> 8, rr = t & 255;
        int b = rr >> 4, chunk = rr & 15, m0 = chunk * 128;
        const float* w1l  = fw1 + (size_t)(j + 1) * NDIM * NHID;
        const float* b1l  = fb1 + (size_t)(j + 1) * NHID;
        const float* fw2l = fw2 + (size_t)j * NHID * NVEC;
        float* xs  = hbuf;               // [128][33] scalar
        float* w1s = hbuf + 128 * 33;    // [32][132]
#pragma unroll
        for (int jj = 0; jj < 2; ++jj) {
            int i4 = tid + jj * 512;     // 1024 f4
            int r = i4 >> 3, c4 = (i4 & 7) * 4;
            int idx = data[b * NVEC + m0 + r];
            float4 v = *(const float4*)&emb[(size_t)idx * NDIM + c4];
            xs[r * 33 + c4] = v.x; xs[r * 33 + c4 + 1] = v.y;
            xs[r * 33 + c4 + 2] = v.z; xs[r * 33 + c4 + 3] = v.w;
        }
#pragma unroll
        for (int jj = 0; jj < 2; ++jj) {
            int i4 = tid + jj * 512;     // 1024 f4
            int d = i4 >> 5, c4 = (i4 & 31) * 4;
            *(float4*)&w1s[d * 132 + c4] = *(const float4*)&w1l[d * NHID + c4];
        }
        // stage the full fw2 chunk: ws[p][m] (coalesced f4)
#pragma unroll
        for (int jj = 0; jj < 8; ++jj) {
            int i4 = tid + jj * 512;     // 4096 f4 = 128 p x 32 f4
            int p = i4 >> 5, c4 = (i4 & 31) * 4;
            *(float4*)&ws[p * 132 + c4] =
                *(const float4*)&fw2l[(size_t)p * NVEC + m0 + c4];
        }
        if (tid < 128) fb2s[tid] = fb2[(size_t)j * NVEC + m0 + tid];
        __syncthreads();

        // ---- h-phase (regs): thread (rg, kg): rows rg+32i (4) x 8 k
        int rg = tid & 31, kg = tid >> 5, k0 = kg * 8;   // kg 0..15
        {
            float hr[4][8];
            float4 b0 = *(const float4*)&b1l[k0];
            float4 b1v = *(const float4*)&b1l[k0 + 4];
            float bk[8] = {b0.x, b0.y, b0.z, b0.w, b1v.x, b1v.y, b1v.z, b1v.w};
#pragma unroll
            for (int i = 0; i < 4; ++i)
#pragma unroll
                for (int q = 0; q < 8; ++q) hr[i][q] = bk[q];
#pragma unroll 4
            for (int d = 0; d < NDIM; ++d) {
                float xv[4];
#pragma unroll
                for (int i = 0; i < 4; ++i) xv[i] = xs[(rg + 32 * i) * 33 + d];
                const float* wrow = &w1s[d * 132 + k0];      // broadcast
                float4 w0 = *(const float4*)wrow;
                float4 w1 = *(const float4*)(wrow + 4);
                float wk[8] = {w0.x, w0.y, w0.z, w0.w, w1.x, w1.y, w1.z, w1.w};
#pragma unroll
                for (int i = 0; i < 4; ++i)
#pragma unroll
                    for (int q = 0; q < 8; ++q) hr[i][q] += xv[i] * wk[q];
            }
            __syncthreads();             // xs/w1s dead
#pragma unroll
            for (int i = 0; i < 4; ++i) {
                int row = rg + 32 * i;
                float4 o0, o1;
                o0.x = gelu_fast(hr[i][0]); o0.y = gelu_fast(hr[i][1]);
                o0.z = gelu_fast(hr[i][2]); o0.w = gelu_fast(hr[i][3]);
                o1.x = gelu_fast(hr[i][4]); o1.y = gelu_fast(hr[i][5]);
                o1.z = gelu_fast(hr[i][6]); o1.w = gelu_fast(hr[i][7]);
                *(float4*)&hbuf[row * 132 + k0]     = o0;
                *(float4*)&hbuf[row * 132 + k0 + 4] = o1;
                if (kg == 0) hbuf[row * 132 + 128] = 1.0f;
            }
        }
        __syncthreads();

        // ---- T-phase: thread (pg, qg, mh) = (tid&15, (tid>>4)&15, tid>>8):
        // 8p x 8q x 64m. Both operands LDS (bank-clean: w 2-way=free,
        // h 4-addr broadcast at slots {0,8,16,24}).
        int pg = tid & 15, qg = (tid >> 4) & 15, mh = tid >> 8;
        int q0 = qg * 8, mbase = mh * 64;
        float acc[8][8];
#pragma unroll
        for (int i = 0; i < 8; ++i)
#pragma unroll
            for (int q = 0; q < 8; ++q) acc[i][q] = 0.f;
        for (int mt = mbase; mt < mbase + 64; mt += 4) {
            float4 wv4[8];
#pragma unroll
            for (int i = 0; i < 8; ++i)
                wv4[i] = *(const float4*)&ws[(pg + 16 * i) * 132 + mt];
            float4 ha[4], hb[4];
#pragma unroll
            for (int mm = 0; mm < 4; ++mm) {
                ha[mm] = *(const float4*)&hbuf[(mt + mm) * 132 + q0];
                hb[mm] = *(const float4*)&hbuf[(mt + mm) * 132 + q0 + 4];
            }
#pragma unroll
            for (int i = 0; i < 8; ++i) {
                const float* wf = (const float*)&wv4[i];
#pragma unroll
                for (int mm = 0; mm < 4; ++mm) {
                    float w = wf[mm];
                    acc[i][0] += w * ha[mm].x; acc[i][1] += w * ha[mm].y;
                    acc[i][2] += w * ha[mm].z; acc[i][3] += w * ha[mm].w;
                    acc[i][4] += w * hb[mm].x; acc[i][5] += w * hb[mm].y;
                    acc[i][6] += w * hb[mm].z; acc[i][7] += w * hb[mm].w;
                }
            }
        }
        __syncthreads();                 // all ws/hbuf T-reads done

        // tails into registers BEFORE merge overwrites ws
        float scol = 0.f, brow = 0.f;
        if (tid < 128) {
#pragma unroll 8
            for (int mm = 0; mm < 128; ++mm) scol += ws[tid * 132 + mm];
        }
        if (tid < 129) {
#pragma unroll 8
            for (int mm = 0; mm < 128; ++mm) brow += fb2s[mm] * hbuf[mm * 132 + tid];
        }
        __syncthreads();                 // tail reads done

        if (mh == 1) {                   // publish upper-m partials into ws
#pragma unroll
            for (int i = 0; i < 8; ++i) {
                *(float4*)&ws[(pg + 16 * i) * 132 + q0] =
                    make_float4(acc[i][0], acc[i][1], acc[i][2], acc[i][3]);
                *(float4*)&ws[(pg + 16 * i) * 132 + q0 + 4] =
                    make_float4(acc[i][4], acc[i][5], acc[i][6], acc[i][7]);
            }
        }
        __syncthreads();

        float* Tp = Tpart + (size_t)t * TPSZ;
        if (mh == 0) {                   // merge + store
#pragma unroll
            for (int i = 0; i < 8; ++i) {
                float4 p0 = *(const float4*)&ws[(pg + 16 * i) * 132 + q0];
                float4 p1 = *(const float4*)&ws[(pg + 16 * i) * 132 + q0 + 4];
                *(float4*)&Tp[(pg + 16 * i) * 132 + q0] =
                    make_float4(acc[i][0] + p0.x, acc[i][1] + p0.y,
                                acc[i][2] + p0.z, acc[i][3] + p0.w);
                *(float4*)&Tp[(pg + 16 * i) * 132 + q0 + 4] =
                    make_float4(acc[i][4] + p1.x, acc[i][5] + p1.y,
                                acc[i][6] + p1.z, acc[i][7] + p1.w);
            }
        }
        if (tid < 128) Tp[tid * 132 + 128] = scol;
        if (tid < 129) Tp[128 * 132 + tid] = brow;
    }
}

// ---------------------------------------------------------------------------
// K2: reduce the 16 m-chunk partials per (j,b) T and per-b U3. grid (17,64).
__global__ __launch_bounds__(256) void k_red(const float* __restrict__ Tpart,
                                             const float* __restrict__ U3part,
                                             float* __restrict__ Tfin,
                                             float* __restrict__ U3fin) {
    int x = blockIdx.x, y = blockIdx.y, tid = threadIdx.x;
    if (y < 48) {                        // y = j*16 + b; slot = y*16 + c
        int i4 = x * 256 + tid;
        if (i4 >= TP4) return;
        float4 s = ((const float4*)Tpart)[(size_t)(y * 16) * TP4 + i4];
#pragma unroll
        for (int c = 1; c < 16; ++c) {
            float4 v = ((const float4*)Tpart)[(size_t)(y * 16 + c) * TP4 + i4];
            s.x += v.x; s.y += v.y; s.z += v.z; s.w += v.w;
        }
        ((float4*)Tfin)[(size_t)y * TP4 + i4] = s;
    } else {
        int b = y - 48;
        int i4 = x * 256 + tid;
        if (i4 >= U4) return;
        float4 s = ((const float4*)U3part)[(size_t)(b * 16) * U4 + i4];
#pragma unroll
        for (int c = 1; c < 16; ++c) {
            float4 v = ((const float4*)U3part)[(size_t)(b * 16 + c) * U4 + i4];
            s.x += v.x; s.y += v.y; s.z += v.z; s.w += v.w;
        }
        ((float4*)U3fin)[(size_t)b * U4 + i4] = s;
    }
}

// ---------------------------------------------------------------------------
// K3: U0 = T0 @ T1 @ T2 @ U3hat, column-independent. grid (8, NB).
__global__ __launch_bounds__(256) void k_chain(const float* __restrict__ Tfin,
                                               const float* __restrict__ U3fin,
                                               const float* __restrict__ bf,
                                               float* __restrict__ U0,
                                               float* __restrict__ out) {
    __shared__ float Ul[2][129 * 4];
    int dg = blockIdx.x, b = blockIdx.y, tid = threadIdx.x;
    int d0 = dg * 4;
    if (dg == 0 && tid < NCLASS) out[b * NCLASS + tid] = bf[tid];
    if (tid < 129)
        *(float4*)&Ul[0][tid * 4] =
            *(const float4*)&U3fin[(size_t)b * USZ + tid * 32 + d0];
    int cur = 0;
    float4 acc = make_float4(0.f, 0.f, 0.f, 0.f);
    for (int j = 2; j >= 0; --j) {
        __syncthreads();
        if (tid < 129) {
            const float* rowp = Tfin + (size_t)(j * 16 + b) * TPSZ + tid * 132;
            acc = make_float4(0.f, 0.f, 0.f, 0.f);
            for (int r4 = 0; r4 < 32; ++r4) {
                float4 tv = *(const float4*)&rowp[4 * r4];
                float4 u0 = *(const float4*)&Ul[cur][(4 * r4 + 0) * 4];
                float4 u1 = *(const float4*)&Ul[cur][(4 * r4 + 1) * 4];
                float4 u2 = *(const float4*)&Ul[cur][(4 * r4 + 2) * 4];
                float4 u3 = *(const float4*)&Ul[cur][(4 * r4 + 3) * 4];
                acc.x += tv.x * u0.x + tv.y * u1.x + tv.z * u2.x + tv.w * u3.x;
                acc.y += tv.x * u0.y + tv.y * u1.y + tv.z * u2.y + tv.w * u3.y;
                acc.z += tv.x * u0.z + tv.y * u1.z + tv.z * u2.z + tv.w * u3.z;
                acc.w += tv.x * u0.w + tv.y * u1.w + tv.z * u2.w + tv.w * u3.w;
            }
            float tl = rowp[128];
            float4 ub = *(const float4*)&Ul[cur][128 * 4];
            acc.x += tl * ub.x; acc.y += tl * ub.y;
            acc.z += tl * ub.z; acc.w += tl * ub.w;
        }
        __syncthreads();
        if (tid < 129) *(float4*)&Ul[cur ^ 1][tid * 4] = acc;
        cur ^= 1;
    }
    if (tid < 129)
        *(float4*)&U0[(size_t)b * USZ + tid * 32 + d0] = acc;
}

// ---------------------------------------------------------------------------
// K4: final V = h_0 @ U0hat + classifier. grid (32, NB).
__global__ __launch_bounds__(256) void k_final(const float* __restrict__ X,
                                               const float* __restrict__ fw1,
                                               const float* __restrict__ fb1,
                                               const float* __restrict__ U0,
                                               const float* __restrict__ Wf,
                                               float* __restrict__ out) {
    __shared__ float xs[64 * 36];
    __shared__ float w1s[32 * 132];
    __shared__ float hs[64 * 132];
    __shared__ float Us[USZ];
    __shared__ float ored[4][NCLASS];
    int ng = blockIdx.x, b = blockIdx.y, tid = threadIdx.x;
    int n0 = ng * 64;
#pragma unroll
    for (int jj = 0; jj < 2; ++jj) {
        int i4 = tid + jj * 256;
        int r = i4 >> 3, c4 = (i4 & 7) * 4;
        *(float4*)&xs[r * 36 + c4] =
            *(const float4*)&X[((size_t)b * NVEC + n0 + r) * NDIM + c4];
    }
#pragma unroll
    for (int jj = 0; jj < 4; ++jj) {
        int i4 = tid + jj * 256;
        int d = i4 >> 5, c4 = (i4 & 31) * 4;
        *(float4*)&w1s[d * 132 + c4] = *(const float4*)&fw1[d * NHID + c4];
    }
    for (int i4 = tid; i4 < U4; i4 += 256)
        ((float4*)Us)[i4] = ((const float4*)(U0 + (size_t)b * USZ))[i4];
    __syncthreads();

    int rg = tid & 31;
    {   // h: rows {rg, rg+32} x 16 k
        int k0 = (tid >> 5) * 16;
        float acc[2][16];
        {
            float4 bq[4];
#pragma unroll
            for (int q = 0; q < 4; ++q) bq[q] = *(const float4*)&fb1[k0 + 4 * q];
#pragma unroll
            for (int q = 0; q < 4; ++q) {
                acc[0][4 * q] = bq[q].x; acc[0][4 * q + 1] = bq[q].y;
                acc[0][4 * q + 2] = bq[q].z; acc[0][4 * q + 3] = bq[q].w;
                acc[1][4 * q] = bq[q].x; acc[1][4 * q + 1] = bq[q].y;
                acc[1][4 * q + 2] = bq[q].z; acc[1][4 * q + 3] = bq[q].w;
            }
        }
#pragma unroll 4
        for (int d = 0; d < NDIM; ++d) {
            float x0 = xs[rg * 36 + d];
            float x1 = xs[(rg + 32) * 36 + d];
            const float* wrow = &w1s[d * 132 + k0];
            float4 w0 = *(const float4*)wrow;
            float4 w1 = *(const float4*)(wrow + 4);
            float4 w2 = *(const float4*)(wrow + 8);
            float4 w3 = *(const float4*)(wrow + 12);
            float wk[16] = {w0.x, w0.y, w0.z, w0.w, w1.x, w1.y, w1.z, w1.w,
                            w2.x, w2.y, w2.z, w2.w, w3.x, w3.y, w3.z, w3.w};
#pragma unroll
            for (int q = 0; q < 16; ++q) {
                acc[0][q] += x0 * wk[q];
                acc[1][q] += x1 * wk[q];
            }
        }
#pragma unroll
        for (int r = 0; r < 2; ++r) {
            int row = rg + 32 * r;
#pragma unroll
            for (int q4 = 0; q4 < 4; ++q4) {
                float4 o;
                o.x = gelu_fast(acc[r][4 * q4]);     o.y = gelu_fast(acc[r][4 * q4 + 1]);
                o.z = gelu_fast(acc[r][4 * q4 + 2]); o.w = gelu_fast(acc[r][4 * q4 + 3]);
                *(float4*)&hs[row * 132 + k0 + 4 * q4] = o;
            }
        }
    }
    __syncthreads();

    int dg = (tid >> 5) & 3, kh = tid >> 7;
    int d0 = dg * 8, kb = kh * 64;
    float a[2][8];
#pragma unroll
    for (int r = 0; r < 2; ++r)
#pragma unroll
        for (int q = 0; q < 8; ++q) a[r][q] = 0.f;
#pragma unroll 4
    for (int ks = 0; ks < 64; ks += 4) {
        int kk = kb + ks;
        float4 h0 = *(const float4*)&hs[rg * 132 + kk];
        float4 h1 = *(const float4*)&hs[(rg + 32) * 132 + kk];
        float4 u[4][2];
#pragma unroll
        for (int q = 0; q < 4; ++q) {
            u[q][0] = *(const float4*)&Us[(kk + q) * 32 + d0];
            u[q][1] = *(const float4*)&Us[(kk + q) * 32 + d0 + 4];
        }
        const float* hf0 = (const float*)&h0;
        const float* hf1 = (const float*)&h1;
#pragma unroll
        for (int q = 0; q < 4; ++q) {
            float v0 = hf0[q], v1 = hf1[q];
            a[0][0] += v0 * u[q][0].x; a[0][1] += v0 * u[q][0].y;
            a[0][2] += v0 * u[q][0].z; a[0][3] += v0 * u[q][0].w;
            a[0][4] += v0 * u[q][1].x; a[0][5] += v0 * u[q][1].y;
            a[0][6] += v0 * u[q][1].z; a[0][7] += v0 * u[q][1].w;
            a[1][0] += v1 * u[q][0].x; a[1][1] += v1 * u[q][0].y;
            a[1][2] += v1 * u[q][0].z; a[1][3] += v1 * u[q][0].w;
            a[1][4] += v1 * u[q][1].x; a[1][5] += v1 * u[q][1].y;
            a[1][6] += v1 * u[q][1].z; a[1][7] += v1 * u[q][1].w;
        }
    }
    if (kh == 1) {
#pragma unroll
        for (int r = 0; r < 2; ++r) {
            float* p = &xs[(rg + 32 * r) * 36 + d0];
            *(float4*)p       = make_float4(a[r][0], a[r][1], a[r][2], a[r][3]);
            *(float4*)(p + 4) = make_float4(a[r][4], a[r][5], a[r][6], a[r][7]);
        }
    }
    __syncthreads();
    float accC[NCLASS];
#pragma unroll
    for (int c = 0; c < NCLASS; ++c) accC[c] = 0.f;
    if (kh == 0) {
        float4 ub0 = *(const float4*)&Us[128 * 32 + d0];
        float4 ub1 = *(const float4*)&Us[128 * 32 + d0 + 4];
#pragma unroll
        for (int r = 0; r < 2; ++r) {
            const float* p = &xs[(rg + 32 * r) * 36 + d0];
            float4 p0 = *(const float4*)p;
            float4 p1 = *(const float4*)(p + 4);
            a[r][0] += p0.x + ub0.x; a[r][1] += p0.y + ub0.y;
            a[r][2] += p0.z + ub0.z; a[r][3] += p0.w + ub0.w;
            a[r][4] += p1.x + ub1.x; a[r][5] += p1.y + ub1.y;
            a[r][6] += p1.z + ub1.z; a[r][7] += p1.w + ub1.w;
            int nrow = n0 + rg + 32 * r;
#pragma unroll
            for (int dd = 0; dd < 8; ++dd) {
                float v = a[r][dd];
                const float2* wr =
                    (const float2*)(Wf + ((size_t)nrow * 32 + d0 + dd) * NCLASS);
#pragma unroll
                for (int p5 = 0; p5 < 5; ++p5) {
                    float2 w = wr[p5];
                    accC[2 * p5]     += v * w.x;
                    accC[2 * p5 + 1] += v * w.y;
                }
            }
        }
    }
#pragma unroll
    for (int c = 0; c < NCLASS; ++c)
#pragma unroll
        for (int off = 32; off >= 1; off >>= 1)
            accC[c] += __shfl_down(accC[c], off, 64);
    int w = tid >> 6;
    if ((tid & 63) == 0) {
#pragma unroll
        for (int c = 0; c < NCLASS; ++c) ored[w][c] = accC[c];
    }
    __syncthreads();
    if (tid < NCLASS)
        atomicAdd(&out[b * NCLASS + tid],
                  ored[0][tid] + ored[1][tid] + ored[2][tid] + ored[3][tid]);
}

// ---------------------------------------------------------------------------
extern "C" void kernel_launch(void* const* d_in, const int* in_sizes, int n_in,
                              void* d_out, int out_size, void* d_ws, size_t ws_size,
                              hipStream_t stream) {
    const int*   data = (const int*)d_in[0];
    const float* emb  = (const float*)d_in[1];
    const float* fw1  = (const float*)d_in[2];
    const float* fb1  = (const float*)d_in[3];
    const float* fw2  = (const float*)d_in[4];
    const float* fb2  = (const float*)d_in[5];
    const float* Wf   = (const float*)d_in[6];
    const float* bf   = (const float*)d_in[7];
    float* out = (float*)d_out;

    float* X      = (float*)d_ws;                       // 1,048,576 floats
    float* Tpart  = X + (size_t)NB * NVEC * NDIM;       // 768*17028 = 13,077,504
    float* U3part = Tpart + (size_t)768 * TPSZ;         // 256*4128  =  1,056,768
    float* Tfin   = U3part + (size_t)256 * USZ;         // 48*17028  =    817,344
    float* U3fin  = Tfin + (size_t)48 * TPSZ;           // 16*4128
    float* U0     = U3fin + (size_t)NB * USZ;           // 16*4128

    k_big<<<1024, 512, 0, stream>>>(data, emb, fw1, fb1, fw2, fb2, X, Tpart, U3part);
    k_red<<<dim3(17, 64), 256, 0, stream>>>(Tpart, U3part, Tfin, U3fin);
    k_chain<<<dim3(8, NB), 256, 0, stream>>>(Tfin, U3fin, bf, U0, out);
    k_final<<<dim3(32, NB), 256, 0, stream>>>(X, fw1, fb1, U0, Wf, out);
}